// Round 11
// baseline (19881.238 us; speedup 1.0000x reference)
//
#include <hip/hip_runtime.h>
#include <hip/hip_bf16.h>
#include <hip/hip_fp16.h>

// Problem constants (fixed by the reference)
#define FDIM 128      // F_IN == H == 128
#define G4H  512      // 4*H

typedef float f32x4 __attribute__((ext_vector_type(4)));
typedef _Float16 f16x8 __attribute__((ext_vector_type(8)));

union frag_cast { f32x4 f; f16x8 h; };
union bperm_cast { int i[4]; f16x8 h; };

// LDS-only barrier: does NOT drain vmcnt (global ops stay in flight).
#define LDS_BARRIER() asm volatile("s_waitcnt lgkmcnt(0)\n\ts_barrier" ::: "memory")

#define AS1 __attribute__((address_space(1)))
#define AS3 __attribute__((address_space(3)))
// Async global->LDS, 16B/lane: LDS dst = uniform base + lane*16.
__device__ __forceinline__ void load_lds16(const float* g, float* l) {
    __builtin_amdgcn_global_load_lds((const AS1 unsigned int*)g,
                                     (AS3 unsigned int*)l, 16, 0, 0);
}

// ---------------------------------------------------------------------------
// degree / normalization
// ---------------------------------------------------------------------------
__global__ void deg_kernel(const int* __restrict__ ei, int* __restrict__ deg, int E) {
    int e = blockIdx.x * 256 + threadIdx.x;
    if (e < E) atomicAdd(&deg[ei[E + e]], 1);
}

__global__ void dinv_kernel(const int* __restrict__ deg, float* __restrict__ dinv, int N) {
    int n = blockIdx.x * 256 + threadIdx.x;
    if (n < N) dinv[n] = rsqrtf((float)(deg[n] + 1));   // +1 self-loop
}

// ---------------------------------------------------------------------------
// CSR build: exclusive scan of deg (1024 thr x 20 nodes), then edge scatter.
// ---------------------------------------------------------------------------
__global__ __launch_bounds__(1024) void scan_kernel(const int* __restrict__ deg,
                                                    int* __restrict__ rs,
                                                    int* __restrict__ cursor,
                                                    int N, int E) {
    __shared__ int buf[2][1024];
    const int t = threadIdx.x;
    const int base = t * 20;
    int loc[20]; int s = 0;
    #pragma unroll
    for (int i = 0; i < 20; ++i) {
        int n = base + i;
        int d = (n < N) ? deg[n] : 0;
        loc[i] = s; s += d;
    }
    buf[0][t] = s; __syncthreads();
    int pb = 0;
    for (int off = 1; off < 1024; off <<= 1) {
        int v = buf[pb][t] + ((t >= off) ? buf[pb][t - off] : 0);
        buf[pb ^ 1][t] = v; pb ^= 1; __syncthreads();
    }
    int pre = (t > 0) ? buf[pb][t - 1] : 0;   // exclusive prefix
    #pragma unroll
    for (int i = 0; i < 20; ++i) {
        int n = base + i;
        if (n < N) { int v = pre + loc[i]; rs[n] = v; cursor[n] = v; }
    }
    if (t == 0) rs[N] = E;
}

__global__ void scatter_kernel(const int* __restrict__ ei, int* __restrict__ cursor,
                               int* __restrict__ csr_src, int E) {
    int e = blockIdx.x * 256 + threadIdx.x;
    if (e >= E) return;
    int s = ei[e], d = ei[E + e];
    int pos = atomicAdd(&cursor[d], 1);
    csr_src[pos] = s;
}

// ---------------------------------------------------------------------------
// C[M x 128] = A[M x 128] @ B[128 x 128]   (B is K-major: B[k*128 + j])
// ---------------------------------------------------------------------------
__global__ __launch_bounds__(256) void gemm_nn(const float* __restrict__ A,
                                               const float* __restrict__ B,
                                               float* __restrict__ C, int M) {
    __shared__ float Bl[64 * 132];
    __shared__ float Al[32][FDIM];
    const int tid = threadIdx.x;
    const int row0 = blockIdx.x * 32;

    for (int i = tid * 4; i < 32 * FDIM; i += 1024) {
        int r = i >> 7, k = i & 127;
        int row = row0 + r;
        float4 v = make_float4(0.f, 0.f, 0.f, 0.f);
        if (row < M) v = *(const float4*)(A + (size_t)row * FDIM + k);
        *(float4*)&Al[r][k] = v;
    }

    const int jg = tid & 31, rg = tid >> 5;
    float acc[4][4] = {};

    for (int kh = 0; kh < 2; ++kh) {
        __syncthreads();
        for (int i = tid * 4; i < 64 * FDIM; i += 1024) {
            int k = i >> 7, j = i & 127;
            *(float4*)&Bl[k * 132 + j] = *(const float4*)(B + (size_t)(kh * 64 + k) * FDIM + j);
        }
        __syncthreads();
        #pragma unroll 4
        for (int k = 0; k < 64; ++k) {
            float4 b4 = *(const float4*)&Bl[k * 132 + jg * 4];
            #pragma unroll
            for (int rr = 0; rr < 4; ++rr) {
                float a = Al[rg * 4 + rr][kh * 64 + k];
                acc[rr][0] += a * b4.x; acc[rr][1] += a * b4.y;
                acc[rr][2] += a * b4.z; acc[rr][3] += a * b4.w;
            }
        }
    }
    #pragma unroll
    for (int rr = 0; rr < 4; ++rr) {
        int row = row0 + rg * 4 + rr;
        if (row < M) {
            float4 v = make_float4(acc[rr][0], acc[rr][1], acc[rr][2], acc[rr][3]);
            *(float4*)(C + (size_t)row * FDIM + jg * 4) = v;
        }
    }
}

// ---------------------------------------------------------------------------
// xg[M x 512] = A[M x 128] @ B^T  (+ b_ih + b_hh), B is [512 x 128] row-major.
// ---------------------------------------------------------------------------
__global__ __launch_bounds__(256) void gemm_nt_xg(const float* __restrict__ A,
                                                  const float* __restrict__ B,
                                                  const float* __restrict__ bih,
                                                  const float* __restrict__ bhh,
                                                  float* __restrict__ C, int M) {
    __shared__ float Bl[64 * 132];
    __shared__ float Al[32][FDIM];
    const int tid = threadIdx.x;
    const int row0 = blockIdx.x * 32;
    const int chunk = blockIdx.y;

    for (int i = tid * 4; i < 32 * FDIM; i += 1024) {
        int r = i >> 7, k = i & 127;
        int row = row0 + r;
        float4 v = make_float4(0.f, 0.f, 0.f, 0.f);
        if (row < M) v = *(const float4*)(A + (size_t)row * FDIM + k);
        *(float4*)&Al[r][k] = v;
    }

    const int jg = tid & 31, rg = tid >> 5;
    float acc[4][4] = {};

    for (int kh = 0; kh < 2; ++kh) {
        __syncthreads();
        for (int i = tid * 4; i < 128 * 64; i += 1024) {
            int g = i >> 6, kl = i & 63;
            float4 v = *(const float4*)(B + (size_t)(chunk * 128 + g) * FDIM + kh * 64 + kl);
            Bl[(kl + 0) * 132 + g] = v.x;
            Bl[(kl + 1) * 132 + g] = v.y;
            Bl[(kl + 2) * 132 + g] = v.z;
            Bl[(kl + 3) * 132 + g] = v.w;
        }
        __syncthreads();
        #pragma unroll 4
        for (int k = 0; k < 64; ++k) {
            float4 b4 = *(const float4*)&Bl[k * 132 + jg * 4];
            #pragma unroll
            for (int rr = 0; rr < 4; ++rr) {
                float a = Al[rg * 4 + rr][kh * 64 + k];
                acc[rr][0] += a * b4.x; acc[rr][1] += a * b4.y;
                acc[rr][2] += a * b4.z; acc[rr][3] += a * b4.w;
            }
        }
    }
    const int col0 = chunk * 128 + jg * 4;
    float4 bsum = make_float4(bih[col0 + 0] + bhh[col0 + 0],
                              bih[col0 + 1] + bhh[col0 + 1],
                              bih[col0 + 2] + bhh[col0 + 2],
                              bih[col0 + 3] + bhh[col0 + 3]);
    #pragma unroll
    for (int rr = 0; rr < 4; ++rr) {
        int row = row0 + rg * 4 + rr;
        if (row < M) {
            float4 v = make_float4(acc[rr][0] + bsum.x, acc[rr][1] + bsum.y,
                                   acc[rr][2] + bsum.z, acc[rr][3] + bsum.w);
            *(float4*)(C + (size_t)row * G4H + col0) = v;
        }
    }
}

// ---------------------------------------------------------------------------
// Fused GCN aggregation (CSR gather): one wave per node, registers, one write.
// ---------------------------------------------------------------------------
__global__ __launch_bounds__(256) void agg_gather(const float* __restrict__ y,
                                                  const int* __restrict__ rs,
                                                  const int* __restrict__ csr_src,
                                                  const float* __restrict__ dinv,
                                                  const float* __restrict__ bias,
                                                  float* __restrict__ o, int N) {
    const int node = blockIdx.x * 4 + (threadIdx.x >> 6);
    if (node >= N) return;
    const int lane = threadIdx.x & 63;
    const int beg = rs[node], end = rs[node + 1];
    const float dn = dinv[node];

    float2 yv = *(const float2*)(y + (size_t)node * FDIM + lane * 2);
    float2 acc = make_float2(yv.x * dn * dn, yv.y * dn * dn);

    for (int base = beg; base < end; base += 64) {
        int cnt = end - base; if (cnt > 64) cnt = 64;
        int msrc = 0; float mnrm = 0.f;
        if (lane < cnt) {
            msrc = csr_src[base + lane];
            mnrm = dinv[msrc] * dn;
        }
        for (int j = 0; j < cnt; ++j) {
            int s = __shfl(msrc, j);
            float nr = __shfl(mnrm, j);
            float2 v = *(const float2*)(y + (size_t)s * FDIM + lane * 2);
            acc.x += v.x * nr;
            acc.y += v.y * nr;
        }
    }
    float2 b = *(const float2*)(bias + lane * 2);
    acc.x = fmaxf(acc.x + b.x, 0.f);
    acc.y = fmaxf(acc.y + b.y, 0.f);
    *(float2*)(o + (size_t)node * FDIM + lane * 2) = acc;
}

// ---------------------------------------------------------------------------
// Prepack w_hh [512 x 128] fp32 into fp16 MFMA A-fragments (4-wave layout).
// dword idx = (((w*8+rt)*4+kt)*64 + lane)*4 + d
//   wave w (0..3) = gate w; row-tile rt (0..7): rows 128w+16rt+m;
//   lane: m = lane&15, q = lane>>4; k = 32kt + 8q + {2d,2d+1}.
// ---------------------------------------------------------------------------
__global__ void pack_whh(const float* __restrict__ whh, float* __restrict__ whp, int n) {
    int i = blockIdx.x * 256 + threadIdx.x;   // n = 32768 dwords
    if (i >= n) return;
    int d = i & 3, fi = i >> 2;
    int lane = fi & 63, kt = (fi >> 6) & 3, rt = (fi >> 8) & 7, w = fi >> 11;
    int m = lane & 15, q = lane >> 4;
    int r = 128 * w + 16 * rt + m;
    int k = 32 * kt + 8 * q + 2 * d;
    __half lo = __float2half(whh[r * FDIM + k]);
    __half hi = __float2half(whh[r * FDIM + k + 1]);
    unsigned u = ((unsigned)__half_as_ushort(hi) << 16) | (unsigned)__half_as_ushort(lo);
    whp[i] = __uint_as_float(u);
}

// ---------------------------------------------------------------------------
// LSTM v11: ONE barrier per step; h lives in registers.
// 4 waves, wave w = gate w (v10's AGPR-pinned A-frags, 32 MFMA/wave).
// After (redundant) phase B every wave holds h as packed half2/lane
// (h[2l],h[2l+1]); next step's B-frags are assembled in-register with 16
// ds_bpermute_b32 (wave-local, no barrier, no hl buffer). Only cross-wave
// data is gates: double-buffered (2 slots) so <=1-step wave skew can't
// clobber a lagging reader; xg ring widened to 8 slots for the same reason.
// Phase B is replicated on all 4 waves (deterministic -> identical c state),
// which removes the second barrier and the h LDS round-trip entirely.
// ---------------------------------------------------------------------------
__global__ void __launch_bounds__(256)
lstm_kernel(const float* __restrict__ xg, const float* __restrict__ whp,
            float* __restrict__ hs, int T) {
    __shared__ __align__(16) float gates[2][4 * 136];  // [slot][gate*136 + j]
    __shared__ __align__(16) float xr[8][G4H];         // xg ring, slot = step & 7
    const int t = threadIdx.x;
    const int w = t >> 6;          // wave 0..3 = gate w
    const int lane = t & 63;
    const int q = lane >> 4;       // k-quad / C row-quad
    const int n = lane & 15;       // C column

    // Load + pin A-fragments into AGPRs: aw[rt][kt], 8 tiles x 4 kt.
    f16x8 aw[8][4];
    {
        const f32x4* wp4 = (const f32x4*)whp;
        #pragma unroll
        for (int rt = 0; rt < 8; ++rt) {
            #pragma unroll
            for (int kt = 0; kt < 4; ++kt) {
                frag_cast fc;
                fc.f = wp4[((w * 8 + rt) * 4 + kt) * 64 + lane];
                f16x8 tmp = fc.h;
                asm volatile("" : "=a"(aw[rt][kt]) : "0"(tmp));  // pin to AGPR class
            }
        }
    }

    // Per-lane replicated state: h packed half2 (h[2l],h[2l+1]) and c pair.
    int h2 = 0;
    float c0 = 0.f, c1 = 0.f;

    // Prime the xg ring: slots 0..2 (6 outstanding vm ops on wave 2).
    if (w == 2) {
        #pragma unroll
        for (int i = 0; i < 3; ++i) {
            const float* g0 = xg + (size_t)i * G4H + lane * 4;
            load_lds16(g0,       &xr[i][0]);
            load_lds16(g0 + 256, &xr[i][256]);
        }
    }
    __syncthreads();   // pre-loop full barrier (vm ops above have slack)

    const int j0 = 16 * n + 4 * q;  // gates writeout j for lanes n<8
    const int baddr = 16 * q;       // bpermute base: src_lane*4 = (16kt+4q+i)*4

    for (int step = 0; step < T; ++step) {
        // ---- phase A: B-frags via in-register bpermute, then MFMA ----
        bperm_cast bu[4];
        #pragma unroll
        for (int kt = 0; kt < 4; ++kt) {
            #pragma unroll
            for (int i = 0; i < 4; ++i)
                bu[kt].i[i] = __builtin_amdgcn_ds_bpermute(baddr + 64 * kt + 4 * i, h2);
        }
        f32x4 cd[8];
        #pragma unroll
        for (int rt = 0; rt < 8; ++rt) cd[rt] = f32x4{0.f, 0.f, 0.f, 0.f};
        #pragma unroll
        for (int kt = 0; kt < 4; ++kt) {
            f16x8 b = bu[kt].h;
            #pragma unroll
            for (int rt = 0; rt < 8; ++rt)
                cd[rt] = __builtin_amdgcn_mfma_f32_16x16x32_f16(aw[rt][kt], b, cd[rt], 0, 0, 0);
        }
        // Every C column identical; lanes n<8 write tile rt=n to this step's slot.
        {
            int nl = n & 3;
            f32x4 selA = (nl == 0) ? cd[0] : (nl == 1) ? cd[1] : (nl == 2) ? cd[2] : cd[3];
            f32x4 selB = (nl == 0) ? cd[4] : (nl == 1) ? cd[5] : (nl == 2) ? cd[6] : cd[7];
            f32x4 sel = (n < 4) ? selA : selB;
            if (n < 8)
                *(f32x4*)&gates[step & 1][w * 136 + j0] = sel;
        }

        // ---- wave 2: stream xg[step+3] into ring slot (step+3)&7 ----
        if (w == 2) {
            int idx = step + 3; if (idx >= T) idx = T - 1;
            const float* g0 = xg + (size_t)idx * G4H + lane * 4;
            load_lds16(g0,       &xr[(step + 3) & 7][0]);
            load_lds16(g0 + 256, &xr[(step + 3) & 7][256]);
            asm volatile("s_waitcnt vmcnt(6)" ::: "memory");  // slot step&7 landed
        }
        LDS_BARRIER();   // the ONLY barrier in the step

        // ---- phase B: replicated on all 4 waves; lane handles j=2l, 2l+1 ----
        {
            const float* gs = gates[step & 1];
            const float* xs = xr[step & 7];
            float2 q0 = *(const float2*)&gs[0 * 136 + 2 * lane];
            float2 q1 = *(const float2*)&gs[1 * 136 + 2 * lane];
            float2 q2 = *(const float2*)&gs[2 * 136 + 2 * lane];
            float2 q3 = *(const float2*)&gs[3 * 136 + 2 * lane];
            float2 x0 = *(const float2*)&xs[0 * FDIM + 2 * lane];
            float2 x1 = *(const float2*)&xs[1 * FDIM + 2 * lane];
            float2 x2 = *(const float2*)&xs[2 * FDIM + 2 * lane];
            float2 x3 = *(const float2*)&xs[3 * FDIM + 2 * lane];

            float giA = 1.f / (1.f + __expf(-(q0.x + x0.x)));
            float gfA = 1.f / (1.f + __expf(-(q1.x + x1.x)));
            float ggA = 1.f - 2.f / (1.f + __expf(2.f * (q2.x + x2.x)));
            float goA = 1.f / (1.f + __expf(-(q3.x + x3.x)));
            c0 = gfA * c0 + giA * ggA;
            float hA = goA * (1.f - 2.f / (1.f + __expf(2.f * c0)));

            float giB = 1.f / (1.f + __expf(-(q0.y + x0.y)));
            float gfB = 1.f / (1.f + __expf(-(q1.y + x1.y)));
            float ggB = 1.f - 2.f / (1.f + __expf(2.f * (q2.y + x2.y)));
            float goB = 1.f / (1.f + __expf(-(q3.y + x3.y)));
            c1 = gfB * c1 + giB * ggB;
            float hB = goB * (1.f - 2.f / (1.f + __expf(2.f * c1)));

            // pack h into half2 register (RTN, same numerics as v9/v10)
            unsigned lo = __half_as_ushort(__float2half(hA));
            unsigned hi = __half_as_ushort(__float2half(hB));
            h2 = (int)((hi << 16) | lo);

            if (w == 0)
                *(float2*)(hs + (size_t)step * FDIM + 2 * lane) = make_float2(hA, hB);
        }
        // no second barrier: gates double-buffered, xr ring distance-safe
    }
}

// ---------------------------------------------------------------------------
// out[M x 12] = hs[M x 128] @ w_fc^T + b_fc
// ---------------------------------------------------------------------------
__global__ __launch_bounds__(256) void fc_kernel(const float* __restrict__ hs,
                                                 const float* __restrict__ wfc,
                                                 const float* __restrict__ bfc,
                                                 float* __restrict__ out, int M) {
    __shared__ float wl[12 * FDIM];
    __shared__ float bl[12];
    const int tid = threadIdx.x;
    for (int i = tid; i < 12 * FDIM / 4; i += 256)
        ((float4*)wl)[i] = ((const float4*)wfc)[i];
    if (tid < 12) bl[tid] = bfc[tid];
    __syncthreads();

    int i = blockIdx.x * 256 + tid;
    if (i >= M) return;
    const float* hrow = hs + (size_t)i * FDIM;
    float acc[12];
    #pragma unroll
    for (int t = 0; t < 12; ++t) acc[t] = bl[t];
    for (int k = 0; k < FDIM; k += 4) {
        float4 h4 = *(const float4*)(hrow + k);
        #pragma unroll
        for (int t = 0; t < 12; ++t) {
            acc[t] += h4.x * wl[t * FDIM + k] + h4.y * wl[t * FDIM + k + 1]
                    + h4.z * wl[t * FDIM + k + 2] + h4.w * wl[t * FDIM + k + 3];
        }
    }
    #pragma unroll
    for (int t = 0; t < 12; ++t) out[(size_t)i * 12 + t] = acc[t];
}

// ---------------------------------------------------------------------------
extern "C" void kernel_launch(void* const* d_in, const int* in_sizes, int n_in,
                              void* d_out, int out_size, void* d_ws, size_t ws_size,
                              hipStream_t stream) {
    const float* x    = (const float*)d_in[0];
    const int*   ei   = (const int*)  d_in[1];
    const float* W1   = (const float*)d_in[2];
    const float* b1   = (const float*)d_in[3];
    const float* W2   = (const float*)d_in[4];
    const float* b2   = (const float*)d_in[5];
    const float* w_ih = (const float*)d_in[6];
    const float* w_hh = (const float*)d_in[7];
    const float* b_ih = (const float*)d_in[8];
    const float* b_hh = (const float*)d_in[9];
    const float* w_fc = (const float*)d_in[10];
    const float* b_fc = (const float*)d_in[11];

    const int N = in_sizes[0] / FDIM;     // 20000
    const int E = in_sizes[1] / 2;        // 1280000

    float* ws   = (float*)d_ws;
    int*   deg  = (int*)ws;                       // 20480 ints
    float* dinv = ws + 20480;                     // 20480 floats
    float* whp  = ws + 40960;                     // 32768 dwords (packed fragments)
    int*   rs   = (int*)(ws + 73728);             // 20992 ints (N+1 used)
    int*   cur  = (int*)(ws + 94720);             // 20480 ints
    int*   csr  = (int*)(ws + 115200);            // E ints
    float* hB   = ws + 115200 + 1280000;          // N*128
    float* big  = hB + (size_t)N * FDIM;          // xg region (N*512), aliases y/hA
    float* y    = big;                            // N*128 (dead before xg written)
    float* hA   = big + (size_t)N * FDIM;         // h1   (dead before xg written)
    float* xg   = big;                            // N*512
    float* hs   = big + (size_t)N * G4H;          // N*128

    hipMemsetAsync(deg, 0, (size_t)N * sizeof(int), stream);
    deg_kernel<<<(E + 255) / 256, 256, 0, stream>>>(ei, deg, E);
    dinv_kernel<<<(N + 255) / 256, 256, 0, stream>>>(deg, dinv, N);
    scan_kernel<<<1, 1024, 0, stream>>>(deg, rs, cur, N, E);
    scatter_kernel<<<(E + 255) / 256, 256, 0, stream>>>(ei, cur, csr, E);
    pack_whh<<<(32768 + 255) / 256, 256, 0, stream>>>(w_hh, whp, 32768);

    const int gblocks = (N + 31) / 32;
    const int ablocks = (N + 3) / 4;
    // layer 1
    gemm_nn<<<gblocks, 256, 0, stream>>>(x, W1, y, N);
    agg_gather<<<ablocks, 256, 0, stream>>>(y, rs, csr, dinv, b1, hA, N);
    // layer 2
    gemm_nn<<<gblocks, 256, 0, stream>>>(hA, W2, y, N);
    agg_gather<<<ablocks, 256, 0, stream>>>(y, rs, csr, dinv, b2, hB, N);
    // LSTM input projection
    gemm_nt_xg<<<dim3(gblocks, 4), 256, 0, stream>>>(hB, w_ih, b_ih, b_hh, xg, N);
    // sequential LSTM (single CU — the critical path)
    lstm_kernel<<<1, 256, 0, stream>>>(xg, whp, hs, N);
    // final projection
    fc_kernel<<<(N + 255) / 256, 256, 0, stream>>>(hs, w_fc, b_fc, (float*)d_out, N);
}

// Round 12
// 14218.742 us; speedup vs baseline: 1.3982x; 1.3982x over previous
//
#include <hip/hip_runtime.h>
#include <hip/hip_bf16.h>
#include <hip/hip_fp16.h>

// Problem constants (fixed by the reference)
#define FDIM 128      // F_IN == H == 128
#define G4H  512      // 4*H

typedef float f32x4 __attribute__((ext_vector_type(4)));
typedef _Float16 f16x8 __attribute__((ext_vector_type(8)));

union frag_cast { f32x4 f; f16x8 h; };

// LDS-only barrier: does NOT drain vmcnt (global ops stay in flight).
#define LDS_BARRIER() asm volatile("s_waitcnt lgkmcnt(0)\n\ts_barrier" ::: "memory")

#define AS1 __attribute__((address_space(1)))
#define AS3 __attribute__((address_space(3)))
// Async global->LDS, 16B/lane: LDS dst = uniform base + lane*16.
__device__ __forceinline__ void load_lds16(const float* g, float* l) {
    __builtin_amdgcn_global_load_lds((const AS1 unsigned int*)g,
                                     (AS3 unsigned int*)l, 16, 0, 0);
}

// ---------------------------------------------------------------------------
// degree / normalization
// ---------------------------------------------------------------------------
__global__ void deg_kernel(const int* __restrict__ ei, int* __restrict__ deg, int E) {
    int e = blockIdx.x * 256 + threadIdx.x;
    if (e < E) atomicAdd(&deg[ei[E + e]], 1);
}

__global__ void dinv_kernel(const int* __restrict__ deg, float* __restrict__ dinv, int N) {
    int n = blockIdx.x * 256 + threadIdx.x;
    if (n < N) dinv[n] = rsqrtf((float)(deg[n] + 1));   // +1 self-loop
}

// ---------------------------------------------------------------------------
// CSR build: exclusive scan of deg (1024 thr x 20 nodes), then edge scatter.
// ---------------------------------------------------------------------------
__global__ __launch_bounds__(1024) void scan_kernel(const int* __restrict__ deg,
                                                    int* __restrict__ rs,
                                                    int* __restrict__ cursor,
                                                    int N, int E) {
    __shared__ int buf[2][1024];
    const int t = threadIdx.x;
    const int base = t * 20;
    int loc[20]; int s = 0;
    #pragma unroll
    for (int i = 0; i < 20; ++i) {
        int n = base + i;
        int d = (n < N) ? deg[n] : 0;
        loc[i] = s; s += d;
    }
    buf[0][t] = s; __syncthreads();
    int pb = 0;
    for (int off = 1; off < 1024; off <<= 1) {
        int v = buf[pb][t] + ((t >= off) ? buf[pb][t - off] : 0);
        buf[pb ^ 1][t] = v; pb ^= 1; __syncthreads();
    }
    int pre = (t > 0) ? buf[pb][t - 1] : 0;   // exclusive prefix
    #pragma unroll
    for (int i = 0; i < 20; ++i) {
        int n = base + i;
        if (n < N) { int v = pre + loc[i]; rs[n] = v; cursor[n] = v; }
    }
    if (t == 0) rs[N] = E;
}

__global__ void scatter_kernel(const int* __restrict__ ei, int* __restrict__ cursor,
                               int* __restrict__ csr_src, int E) {
    int e = blockIdx.x * 256 + threadIdx.x;
    if (e >= E) return;
    int s = ei[e], d = ei[E + e];
    int pos = atomicAdd(&cursor[d], 1);
    csr_src[pos] = s;
}

// ---------------------------------------------------------------------------
// C[M x 128] = A[M x 128] @ B[128 x 128]   (B is K-major: B[k*128 + j])
// ---------------------------------------------------------------------------
__global__ __launch_bounds__(256) void gemm_nn(const float* __restrict__ A,
                                               const float* __restrict__ B,
                                               float* __restrict__ C, int M) {
    __shared__ float Bl[64 * 132];
    __shared__ float Al[32][FDIM];
    const int tid = threadIdx.x;
    const int row0 = blockIdx.x * 32;

    for (int i = tid * 4; i < 32 * FDIM; i += 1024) {
        int r = i >> 7, k = i & 127;
        int row = row0 + r;
        float4 v = make_float4(0.f, 0.f, 0.f, 0.f);
        if (row < M) v = *(const float4*)(A + (size_t)row * FDIM + k);
        *(float4*)&Al[r][k] = v;
    }

    const int jg = tid & 31, rg = tid >> 5;
    float acc[4][4] = {};

    for (int kh = 0; kh < 2; ++kh) {
        __syncthreads();
        for (int i = tid * 4; i < 64 * FDIM; i += 1024) {
            int k = i >> 7, j = i & 127;
            *(float4*)&Bl[k * 132 + j] = *(const float4*)(B + (size_t)(kh * 64 + k) * FDIM + j);
        }
        __syncthreads();
        #pragma unroll 4
        for (int k = 0; k < 64; ++k) {
            float4 b4 = *(const float4*)&Bl[k * 132 + jg * 4];
            #pragma unroll
            for (int rr = 0; rr < 4; ++rr) {
                float a = Al[rg * 4 + rr][kh * 64 + k];
                acc[rr][0] += a * b4.x; acc[rr][1] += a * b4.y;
                acc[rr][2] += a * b4.z; acc[rr][3] += a * b4.w;
            }
        }
    }
    #pragma unroll
    for (int rr = 0; rr < 4; ++rr) {
        int row = row0 + rg * 4 + rr;
        if (row < M) {
            float4 v = make_float4(acc[rr][0], acc[rr][1], acc[rr][2], acc[rr][3]);
            *(float4*)(C + (size_t)row * FDIM + jg * 4) = v;
        }
    }
}

// ---------------------------------------------------------------------------
// xg[M x 512] = A[M x 128] @ B^T  (+ b_ih + b_hh), B is [512 x 128] row-major.
// ---------------------------------------------------------------------------
__global__ __launch_bounds__(256) void gemm_nt_xg(const float* __restrict__ A,
                                                  const float* __restrict__ B,
                                                  const float* __restrict__ bih,
                                                  const float* __restrict__ bhh,
                                                  float* __restrict__ C, int M) {
    __shared__ float Bl[64 * 132];
    __shared__ float Al[32][FDIM];
    const int tid = threadIdx.x;
    const int row0 = blockIdx.x * 32;
    const int chunk = blockIdx.y;

    for (int i = tid * 4; i < 32 * FDIM; i += 1024) {
        int r = i >> 7, k = i & 127;
        int row = row0 + r;
        float4 v = make_float4(0.f, 0.f, 0.f, 0.f);
        if (row < M) v = *(const float4*)(A + (size_t)row * FDIM + k);
        *(float4*)&Al[r][k] = v;
    }

    const int jg = tid & 31, rg = tid >> 5;
    float acc[4][4] = {};

    for (int kh = 0; kh < 2; ++kh) {
        __syncthreads();
        for (int i = tid * 4; i < 128 * 64; i += 1024) {
            int g = i >> 6, kl = i & 63;
            float4 v = *(const float4*)(B + (size_t)(chunk * 128 + g) * FDIM + kh * 64 + kl);
            Bl[(kl + 0) * 132 + g] = v.x;
            Bl[(kl + 1) * 132 + g] = v.y;
            Bl[(kl + 2) * 132 + g] = v.z;
            Bl[(kl + 3) * 132 + g] = v.w;
        }
        __syncthreads();
        #pragma unroll 4
        for (int k = 0; k < 64; ++k) {
            float4 b4 = *(const float4*)&Bl[k * 132 + jg * 4];
            #pragma unroll
            for (int rr = 0; rr < 4; ++rr) {
                float a = Al[rg * 4 + rr][kh * 64 + k];
                acc[rr][0] += a * b4.x; acc[rr][1] += a * b4.y;
                acc[rr][2] += a * b4.z; acc[rr][3] += a * b4.w;
            }
        }
    }
    const int col0 = chunk * 128 + jg * 4;
    float4 bsum = make_float4(bih[col0 + 0] + bhh[col0 + 0],
                              bih[col0 + 1] + bhh[col0 + 1],
                              bih[col0 + 2] + bhh[col0 + 2],
                              bih[col0 + 3] + bhh[col0 + 3]);
    #pragma unroll
    for (int rr = 0; rr < 4; ++rr) {
        int row = row0 + rg * 4 + rr;
        if (row < M) {
            float4 v = make_float4(acc[rr][0] + bsum.x, acc[rr][1] + bsum.y,
                                   acc[rr][2] + bsum.z, acc[rr][3] + bsum.w);
            *(float4*)(C + (size_t)row * G4H + col0) = v;
        }
    }
}

// ---------------------------------------------------------------------------
// Fused GCN aggregation (CSR gather): one wave per node, registers, one write.
// ---------------------------------------------------------------------------
__global__ __launch_bounds__(256) void agg_gather(const float* __restrict__ y,
                                                  const int* __restrict__ rs,
                                                  const int* __restrict__ csr_src,
                                                  const float* __restrict__ dinv,
                                                  const float* __restrict__ bias,
                                                  float* __restrict__ o, int N) {
    const int node = blockIdx.x * 4 + (threadIdx.x >> 6);
    if (node >= N) return;
    const int lane = threadIdx.x & 63;
    const int beg = rs[node], end = rs[node + 1];
    const float dn = dinv[node];

    float2 yv = *(const float2*)(y + (size_t)node * FDIM + lane * 2);
    float2 acc = make_float2(yv.x * dn * dn, yv.y * dn * dn);

    for (int base = beg; base < end; base += 64) {
        int cnt = end - base; if (cnt > 64) cnt = 64;
        int msrc = 0; float mnrm = 0.f;
        if (lane < cnt) {
            msrc = csr_src[base + lane];
            mnrm = dinv[msrc] * dn;
        }
        for (int j = 0; j < cnt; ++j) {
            int s = __shfl(msrc, j);
            float nr = __shfl(mnrm, j);
            float2 v = *(const float2*)(y + (size_t)s * FDIM + lane * 2);
            acc.x += v.x * nr;
            acc.y += v.y * nr;
        }
    }
    float2 b = *(const float2*)(bias + lane * 2);
    acc.x = fmaxf(acc.x + b.x, 0.f);
    acc.y = fmaxf(acc.y + b.y, 0.f);
    *(float2*)(o + (size_t)node * FDIM + lane * 2) = acc;
}

// ---------------------------------------------------------------------------
// Prepack w_hh [512 x 128] fp32 into fp16 MFMA A-fragments (8-wave layout).
// dword idx = (((w*4+rt)*4+kt)*64 + lane)*4 + d
//   wave w (0..7): gate rows [64w, 64w+64); row-tile rt (0..3);
//   lane: m = lane&15, q = lane>>4; row r = 64w+16rt+m; k = 32kt+8q+{2d,2d+1}.
// ---------------------------------------------------------------------------
__global__ void pack_whh(const float* __restrict__ whh, float* __restrict__ whp, int n) {
    int i = blockIdx.x * 256 + threadIdx.x;   // n = 32768 dwords
    if (i >= n) return;
    int d = i & 3, fi = i >> 2;
    int lane = fi & 63, kt = (fi >> 6) & 3, rt = (fi >> 8) & 3, w = fi >> 10;
    int m = lane & 15, q = lane >> 4;
    int r = 64 * w + 16 * rt + m;
    int k = 32 * kt + 8 * q + 2 * d;
    __half lo = __float2half(whh[r * FDIM + k]);
    __half hi = __float2half(whh[r * FDIM + k + 1]);
    unsigned u = ((unsigned)__half_as_ushort(hi) << 16) | (unsigned)__half_as_ushort(lo);
    whp[i] = __uint_as_float(u);
}

// ---------------------------------------------------------------------------
// LSTM v12 = v9 topology (best measured: 8 waves, 2 LDS-only barriers, gates
// via LDS, phase B on 2 waves, wave-2 xg LDS ring) with the MFMAs issued as
// INLINE ASM consuming the A-fragments DIRECTLY from AGPRs ("a" constraint).
// v7-v11 used the builtin on "=a"-pinned values: AV-class operands made the
// compiler emit v_accvgpr_read copies at every use — 128 copies/wave/step
// = ~500 cyc/step of VALU on the critical path (the constant VALUBusy bill
// across v7/v9/v10). ISA: v_mfma A-operand reads VGPR OR AGPR natively.
// s_nop x2 after the chain covers MFMA->VALU read latency (asm is opaque
// to the compiler's hazard model).
// ---------------------------------------------------------------------------
__global__ void __launch_bounds__(512, 2)
lstm_kernel(const float* __restrict__ xg, const float* __restrict__ whp,
            float* __restrict__ hs, int T) {
    __shared__ __align__(16) __half hl[FDIM];
    __shared__ __align__(16) float gates[4 * 136];   // stride 136 floats per gate
    __shared__ __align__(16) float xr[4][G4H];       // xg ring, slot = step & 3
    const int t = threadIdx.x;
    const int w = t >> 6;          // wave 0..7
    const int lane = t & 63;
    const int q = lane >> 4;       // k-quad / C row-quad
    const int n = lane & 15;       // C column

    // A-fragments, loaded once. All uses below are "a"-constrained asm
    // operands, so the RA allocates them to AGPRs (no spill — proven v6-v11)
    // with no per-use copies.
    f16x8 aw0[4], aw1[4], aw2[4], aw3[4];
    {
        const f32x4* wp4 = (const f32x4*)whp;
        #pragma unroll
        for (int kt = 0; kt < 4; ++kt) {
            frag_cast fc;
            fc.f = wp4[((w * 4 + 0) * 4 + kt) * 64 + lane]; aw0[kt] = fc.h;
            fc.f = wp4[((w * 4 + 1) * 4 + kt) * 64 + lane]; aw1[kt] = fc.h;
            fc.f = wp4[((w * 4 + 2) * 4 + kt) * 64 + lane]; aw2[kt] = fc.h;
            fc.f = wp4[((w * 4 + 3) * 4 + kt) * 64 + lane]; aw3[kt] = fc.h;
        }
    }

    float c = 0.f;
    if (t < FDIM) hl[t] = __float2half(0.f);
    // Prime the xg ring: slots 0..2 (6 outstanding vm ops on wave 2).
    if (w == 2) {
        #pragma unroll
        for (int i = 0; i < 3; ++i) {
            const float* g0 = xg + (size_t)i * G4H + lane * 4;
            load_lds16(g0,       &xr[i][0]);
            load_lds16(g0 + 256, &xr[i][256]);
        }
    }
    __syncthreads();   // pre-loop full barrier (vm ops above have slack)

    const int gsel = w >> 1;                      // this wave's gate
    const int j0 = (w & 1) * 64 + 16 * n + 4 * q; // writeout j (lanes n<4)

    for (int step = 0; step < T; ++step) {
        // ---- phase A: B-frags from LDS, MFMA with direct-AGPR A-operand ----
        f16x8 b0, b1, b2, b3;
        {
            frag_cast bc;
            bc.f = *(const f32x4*)((const char*)hl +   0 + q * 16); b0 = bc.h;
            bc.f = *(const f32x4*)((const char*)hl +  64 + q * 16); b1 = bc.h;
            bc.f = *(const f32x4*)((const char*)hl + 128 + q * 16); b2 = bc.h;
            bc.f = *(const f32x4*)((const char*)hl + 192 + q * 16); b3 = bc.h;
        }
        f32x4 cd0 = {0.f, 0.f, 0.f, 0.f}, cd1 = cd0, cd2 = cd0, cd3 = cd0;
        #define MFMA4(BB)                                                         \
            asm volatile("v_mfma_f32_16x16x32_f16 %0, %1, %2, %0"                 \
                         : "+v"(cd0) : "a"(aw0[ktc]), "v"(BB));                   \
            asm volatile("v_mfma_f32_16x16x32_f16 %0, %1, %2, %0"                 \
                         : "+v"(cd1) : "a"(aw1[ktc]), "v"(BB));                   \
            asm volatile("v_mfma_f32_16x16x32_f16 %0, %1, %2, %0"                 \
                         : "+v"(cd2) : "a"(aw2[ktc]), "v"(BB));                   \
            asm volatile("v_mfma_f32_16x16x32_f16 %0, %1, %2, %0"                 \
                         : "+v"(cd3) : "a"(aw3[ktc]), "v"(BB));
        { enum { ktc = 0 }; MFMA4(b0) }
        { enum { ktc = 1 }; MFMA4(b1) }
        { enum { ktc = 2 }; MFMA4(b2) }
        { enum { ktc = 3 }; MFMA4(b3) }
        #undef MFMA4
        // MFMA->VALU read hazard padding (asm latency invisible to compiler)
        asm volatile("s_nop 7\n\ts_nop 7" ::: "memory");

        // Every C column holds the same values; lanes n<4 write row-tile rt=n.
        f32x4 sel = (n == 0) ? cd0 : (n == 1) ? cd1 : (n == 2) ? cd2 : cd3;
        if (n < 4)
            *(f32x4*)&gates[gsel * 136 + j0] = sel;

        // ---- wave 2: stream xg[step+3] into ring slot (step+3)&3 ----
        if (w == 2) {
            int idx = step + 3; if (idx >= T) idx = T - 1;
            const float* g0 = xg + (size_t)idx * G4H + lane * 4;
            load_lds16(g0,       &xr[idx & 3][0]);
            load_lds16(g0 + 256, &xr[idx & 3][256]);
            // guarantee slot step&3 (issued 3 steps ago) has landed
            asm volatile("s_waitcnt vmcnt(6)" ::: "memory");
        }
        LDS_BARRIER();

        // ---- phase B: 2 waves, thread j: combine + activations + state ----
        if (t < FDIM) {
            const float* xs = xr[step & 3];
            float gi = gates[0 * 136 + t] + xs[0 * FDIM + t];
            float gf = gates[1 * 136 + t] + xs[1 * FDIM + t];
            float gg = gates[2 * 136 + t] + xs[2 * FDIM + t];
            float go = gates[3 * 136 + t] + xs[3 * FDIM + t];
            gi = 1.f / (1.f + __expf(-gi));
            gf = 1.f / (1.f + __expf(-gf));
            gg = 1.f - 2.f / (1.f + __expf(2.f * gg));
            go = 1.f / (1.f + __expf(-go));
            c = gf * c + gi * gg;
            float th = 1.f - 2.f / (1.f + __expf(2.f * c));
            float h = go * th;
            hs[(size_t)step * FDIM + t] = h;   // store: never waited on in-loop
            hl[t] = __float2half(h);
        }
        LDS_BARRIER();
    }
}

// ---------------------------------------------------------------------------
// out[M x 12] = hs[M x 128] @ w_fc^T + b_fc
// ---------------------------------------------------------------------------
__global__ __launch_bounds__(256) void fc_kernel(const float* __restrict__ hs,
                                                 const float* __restrict__ wfc,
                                                 const float* __restrict__ bfc,
                                                 float* __restrict__ out, int M) {
    __shared__ float wl[12 * FDIM];
    __shared__ float bl[12];
    const int tid = threadIdx.x;
    for (int i = tid; i < 12 * FDIM / 4; i += 256)
        ((float4*)wl)[i] = ((const float4*)wfc)[i];
    if (tid < 12) bl[tid] = bfc[tid];
    __syncthreads();

    int i = blockIdx.x * 256 + tid;
    if (i >= M) return;
    const float* hrow = hs + (size_t)i * FDIM;
    float acc[12];
    #pragma unroll
    for (int t = 0; t < 12; ++t) acc[t] = bl[t];
    for (int k = 0; k < FDIM; k += 4) {
        float4 h4 = *(const float4*)(hrow + k);
        #pragma unroll
        for (int t = 0; t < 12; ++t) {
            acc[t] += h4.x * wl[t * FDIM + k] + h4.y * wl[t * FDIM + k + 1]
                    + h4.z * wl[t * FDIM + k + 2] + h4.w * wl[t * FDIM + k + 3];
        }
    }
    #pragma unroll
    for (int t = 0; t < 12; ++t) out[(size_t)i * 12 + t] = acc[t];
}

// ---------------------------------------------------------------------------
extern "C" void kernel_launch(void* const* d_in, const int* in_sizes, int n_in,
                              void* d_out, int out_size, void* d_ws, size_t ws_size,
                              hipStream_t stream) {
    const float* x    = (const float*)d_in[0];
    const int*   ei   = (const int*)  d_in[1];
    const float* W1   = (const float*)d_in[2];
    const float* b1   = (const float*)d_in[3];
    const float* W2   = (const float*)d_in[4];
    const float* b2   = (const float*)d_in[5];
    const float* w_ih = (const float*)d_in[6];
    const float* w_hh = (const float*)d_in[7];
    const float* b_ih = (const float*)d_in[8];
    const float* b_hh = (const float*)d_in[9];
    const float* w_fc = (const float*)d_in[10];
    const float* b_fc = (const float*)d_in[11];

    const int N = in_sizes[0] / FDIM;     // 20000
    const int E = in_sizes[1] / 2;        // 1280000

    float* ws   = (float*)d_ws;
    int*   deg  = (int*)ws;                       // 20480 ints
    float* dinv = ws + 20480;                     // 20480 floats
    float* whp  = ws + 40960;                     // 32768 dwords (packed fragments)
    int*   rs   = (int*)(ws + 73728);             // 20992 ints (N+1 used)
    int*   cur  = (int*)(ws + 94720);             // 20480 ints
    int*   csr  = (int*)(ws + 115200);            // E ints
    float* hB   = ws + 115200 + 1280000;          // N*128
    float* big  = hB + (size_t)N * FDIM;          // xg region (N*512), aliases y/hA
    float* y    = big;                            // N*128 (dead before xg written)
    float* hA   = big + (size_t)N * FDIM;         // h1   (dead before xg written)
    float* xg   = big;                            // N*512
    float* hs   = big + (size_t)N * G4H;          // N*128

    hipMemsetAsync(deg, 0, (size_t)N * sizeof(int), stream);
    deg_kernel<<<(E + 255) / 256, 256, 0, stream>>>(ei, deg, E);
    dinv_kernel<<<(N + 255) / 256, 256, 0, stream>>>(deg, dinv, N);
    scan_kernel<<<1, 1024, 0, stream>>>(deg, rs, cur, N, E);
    scatter_kernel<<<(E + 255) / 256, 256, 0, stream>>>(ei, cur, csr, E);
    pack_whh<<<(32768 + 255) / 256, 256, 0, stream>>>(w_hh, whp, 32768);

    const int gblocks = (N + 31) / 32;
    const int ablocks = (N + 3) / 4;
    // layer 1
    gemm_nn<<<gblocks, 256, 0, stream>>>(x, W1, y, N);
    agg_gather<<<ablocks, 256, 0, stream>>>(y, rs, csr, dinv, b1, hA, N);
    // layer 2
    gemm_nn<<<gblocks, 256, 0, stream>>>(hA, W2, y, N);
    agg_gather<<<ablocks, 256, 0, stream>>>(y, rs, csr, dinv, b2, hB, N);
    // LSTM input projection
    gemm_nt_xg<<<dim3(gblocks, 4), 256, 0, stream>>>(hB, w_ih, b_ih, b_hh, xg, N);
    // sequential LSTM (single CU — the critical path)
    lstm_kernel<<<1, 512, 0, stream>>>(xg, whp, hs, N);
    // final projection
    fc_kernel<<<(N + 255) / 256, 256, 0, stream>>>(hs, w_fc, b_fc, (float*)d_out, N);
}